// Round 3
// baseline (138.945 us; speedup 1.0000x reference)
//
#include <hip/hip_runtime.h>

#define NB 8      // NUM_BLOCK
#define NT 500    // NUM_FRAME
#define NF 257    // NUM_BIN
#define NC 8      // NUM_CH
#define NNUL 4    // NUM_NULL
#define LOWF 5
#define HIGHF 70
#define S_CHUNK 8
#define WARM 4
#define N_CHUNK 63   // ceil(NT / S_CHUNK)
#define AL 0.35f

__device__ __forceinline__ float dot4(const float4& a, const float4& b) {
    return a.x*b.x + a.y*b.y + a.z*b.z + a.w*b.w;
}
__device__ __forceinline__ float4 shq(const float4& v, const int m) {
    float4 r;
    r.x = __shfl_xor(v.x, m); r.y = __shfl_xor(v.y, m);
    r.z = __shfl_xor(v.z, m); r.w = __shfl_xor(v.w, m);
    return r;
}

// R3: full quad-split x loading. R2 was latency/issue-bound (VALU 46%, HBM
// 15%, occ 32%): 4 redundant global_load_dwordx4 per frame per thread (all 4
// lanes of a quad loaded the same 16-float f-row), depth-1 prefetch.
// Now each lane loads ONE float4: parity pA=n&1 picks xr/xi, half h=n>>1
// picks ch[0:4)/[4:8). Wave load = 2x512B contiguous unique. Quad
// reconstructs via 3 quad_perm shuffles: X1=xor1 (other parity, same half),
// X2=xor2 (same parity, other half), X3=xor3. Weight regs are loaded
// channel-half-swapped per lane at init so dots need no runtime selects:
//   dot8(A,w) == dot4(L,wO)+dot4(X2,wX), dot8(B,w) == dot4(X1,wO)+dot4(X3,wX)
// pw via 4-FMA square-sum + quad reduce (xor1+xor2). Prefetch regs 16->4 per
// frame, so depth-2 ping-pong prefetch (frame count is always even: 8 or 12)
// stays <=64 VGPR (8 waves/SIMD). f=256 extra path same treatment.
// Deferred-ratio epilogue (R2) kept: 2 barriers/block total.
__global__ __launch_bounds__(1024, 4) void dcf_fused_kernel(
    const float* __restrict__ x,           // (NB,NT,2,NF,NC) fp32
    const int* __restrict__ beam_id,       // (NB,)
    const float* __restrict__ targ_w,      // (8,2,NF,NC) fp32
    const float* __restrict__ null_w,      // (8,NNUL,2,NF,NC) fp32
    float* __restrict__ out)               // fp32: dcf (NB,NT,NF,NNUL) then targ (NB,NT,2,NF)
{
    const int tid = threadIdx.x;
    const int bid = blockIdx.x;
    const int b  = bid & 7;
    const int k  = bid >> 3;
    const int t0 = k * S_CHUNK;
    const int te = min(NT, t0 + S_CHUNK);
    int ts = t0 - WARM; if (ts < 0) ts = 0;

    const int f = tid >> 2;                // 0..255
    const int n = tid & 3;
    const int wid = tid >> 6;
    const int lane = tid & 63;
    const bool extra = (tid < 4);          // quad 0 of wave 0 -> f=256

    __shared__ float s_w256[16 + 4 * 16];       // f=256 weights: twr,twi then per-n nwr,nwi
    __shared__ float s_part[S_CHUNK][25];       // per-frame ratio partials (waves 0..4 write)
    __shared__ float s_dcf[S_CHUNK][1028];      // pre-ratio dcf: [frame][tid], +4 for f=256

    const int beam = beam_id[b];
    const int pA = n & 1;                  // parity: 0=xr(even n), 1=xi(odd n)
    const int h  = n >> 1;                 // channel half: 0 -> ch[0,4), 1 -> ch[4,8)
    const int co = h * 4;                  // own-half offset
    const int cx = 4 - co;                 // other-half offset
    const int psel = (n == 1 || n == 2) ? 1 : 0;   // targ part for this lane's partial
    const float nsign = pA ? -1.f : 1.f;
    const size_t PSTR = (size_t)NF * NC;   // parity stride (floats)

    // weights in registers, channel-half-swapped per lane (wO = own half)
    float4 twO, twX, nAO, nAX, nBO, nBX;
    {
        const float* tp = targ_w + ((size_t)(beam * 2 + psel) * NF + f) * NC;
        twO = *(const float4*)(tp + co);  twX = *(const float4*)(tp + cx);
        const float* qp = null_w + (((size_t)(beam * NNUL + n) * 2) * NF + f) * NC;
        nAO = *(const float4*)(qp + pA * PSTR + co);
        nAX = *(const float4*)(qp + pA * PSTR + cx);
        nBO = *(const float4*)(qp + (1 - pA) * PSTR + co);
        nBX = *(const float4*)(qp + (1 - pA) * PSTR + cx);
    }
    if (tid < 16) {
        int p = tid >> 3, c = tid & 7;
        s_w256[tid] = targ_w[((size_t)(beam * 2 + p) * NF + 256) * NC + c];
    } else if (tid < 80) {
        int i = tid - 16;
        int nn = i >> 4, p = (i >> 3) & 1, c = i & 7;
        s_w256[tid] = null_w[((size_t)((beam * NNUL + nn) * 2 + p) * NF + 256) * NC + c];
    }
    __syncthreads();   // barrier 1 of 2 (weights visible)

    float phi_r = 0.f, phi_i = 0.f, psd = 0.f;
    float phi_r2 = 0.f, phi_i2 = 0.f, psd2 = 0.f;
    const float a = AL, oma = 1.0f - AL;
    const size_t rowlen = 2 * PSTR;        // 4112 floats per (b,t)
    const bool in_red = (f >= LOWF) && (f < HIGHF);   // waves 0..4 only

    const float* xb = x + (size_t)b * NT * rowlen + pA * PSTR + (size_t)f * NC + co;
    const float* xe = x + (size_t)b * NT * rowlen + pA * PSTR + 256 * NC + co;
    float* outT = out + (size_t)NB * NT * NF * NNUL;

    auto frame = [&](const int t, const float4& L) {
        const float4 X1 = shq(L, 1);       // other parity, same half
        const float4 X2 = shq(L, 2);       // same parity, other half
        const float4 X3 = shq(L, 3);       // other parity, other half

        // targ dots via quad butterfly: lane n's partial d covers
        // n0: xr.twr  n1: xi.twi  n2: xr.twi  n3: xi.twr
        const float d = dot4(L, twO) + dot4(X2, twX);
        const float e = __shfl_xor(d, 1);
        const float u = (n < 2) ? ((n == 0) ? (d - e) : (e - d)) : (d + e);
        const float v = __shfl_xor(u, 2);
        const float tr = (n < 2) ? u : v;
        const float ti = (n < 2) ? v : u;

        // null dots
        const float P  = dot4(L,  nAO) + dot4(X2, nAX);
        const float Q  = dot4(X1, nBO) + dot4(X3, nBX);
        const float nr = nsign * (P - Q);
        const float ni = dot4(L, nBO) + dot4(X2, nBX) + dot4(X1, nAO) + dot4(X3, nAX);

        // pw: own-piece square-sum + quad reduce
        float s = dot4(L, L);
        s += __shfl_xor(s, 1);
        s += __shfl_xor(s, 2);
        const float pw = s * 0.125f;

        if (t == 0) {  // exact asymmetric init from the reference
            phi_r = oma * tr * nr + ti * ni;
            phi_i = oma * ti * nr - tr * ni;
            psd   = oma * pw;
        } else {
            phi_r = a * phi_r + oma * (tr * nr + ti * ni);
            phi_i = a * phi_i + oma * (ti * nr - tr * ni);
            psd   = a * psd + oma * pw;
        }

        // f=256 on quad 0 of wave 0: weights from LDS, x quad-split too
        float tr2 = 0.f, ti2 = 0.f;
        if (extra) {
            const float4 Le = *(const float4*)(xe + (size_t)t * rowlen);
            const float4 Y1 = shq(Le, 1);
            const float4 Y2 = shq(Le, 2);
            const float4 Y3 = shq(Le, 3);
            const float4 etwO = *(const float4*)&s_w256[psel * 8 + co];
            const float4 etwX = *(const float4*)&s_w256[psel * 8 + cx];
            const float* nq = &s_w256[16 + n * 16];
            const float4 enAO = *(const float4*)(nq + pA * 8 + co);
            const float4 enAX = *(const float4*)(nq + pA * 8 + cx);
            const float4 enBO = *(const float4*)(nq + (1 - pA) * 8 + co);
            const float4 enBX = *(const float4*)(nq + (1 - pA) * 8 + cx);
            const float d2 = dot4(Le, etwO) + dot4(Y2, etwX);
            const float e2 = __shfl_xor(d2, 1);
            const float u2 = (n < 2) ? ((n == 0) ? (d2 - e2) : (e2 - d2)) : (d2 + e2);
            const float v2 = __shfl_xor(u2, 2);
            tr2 = (n < 2) ? u2 : v2;
            ti2 = (n < 2) ? v2 : u2;
            const float P2  = dot4(Le, enAO) + dot4(Y2, enAX);
            const float Q2  = dot4(Y1, enBO) + dot4(Y3, enBX);
            const float nr2 = nsign * (P2 - Q2);
            const float ni2 = dot4(Le, enBO) + dot4(Y2, enBX) + dot4(Y1, enAO) + dot4(Y3, enAX);
            float s2 = dot4(Le, Le);
            s2 += __shfl_xor(s2, 1);
            s2 += __shfl_xor(s2, 2);
            const float pw2 = s2 * 0.125f;
            if (t == 0) {
                phi_r2 = oma * tr2 * nr2 + ti2 * ni2;
                phi_i2 = oma * ti2 * nr2 - tr2 * ni2;
                psd2   = oma * pw2;
            } else {
                phi_r2 = a * phi_r2 + oma * (tr2 * nr2 + ti2 * ni2);
                phi_i2 = a * phi_i2 + oma * (ti2 * nr2 - tr2 * ni2);
                psd2   = a * psd2 + oma * pw2;
            }
        }

        if (t >= t0) {
            const int fr = t - t0;
            const float phi = sqrtf(phi_r * phi_r + phi_i * phi_i);
            const float dcfv = fminf(fmaxf(phi / (psd + 1e-13f), 0.01f), 1.0f);
            const size_t bt = (size_t)(b * NT + t);
            if (n == 0) outT[(bt * 2 + 0) * NF + f] = tr;
            if (n == 1) outT[(bt * 2 + 1) * NF + f] = ti;
            s_dcf[fr][tid] = dcfv;                       // pre-ratio, own slot
            if (extra) {
                const float phi2 = sqrtf(phi_r2 * phi_r2 + phi_i2 * phi_i2);
                const float dcf2v = fminf(fmaxf(phi2 / (psd2 + 1e-13f), 0.01f), 1.0f);
                s_dcf[fr][1024 + n] = dcf2v;
                if (n == 0) outT[(bt * 2 + 0) * NF + 256] = tr2;
                if (n == 1) outT[(bt * 2 + 1) * NF + 256] = ti2;
            }
            // ratio partials: waves 0..4 hold f in [5,70); NO barrier here
            if (wid < 5) {
                float v_phi = in_red ? phi : 0.f;
                float v_psd = (in_red && n == 0) ? psd : 0.f;
                #pragma unroll
                for (int off = 4; off < 64; off <<= 1) {
                    v_phi += __shfl_xor(v_phi, off);
                    v_psd += __shfl_xor(v_psd, off);
                }
                if (lane < 4)  s_part[fr][wid * 5 + lane] = v_phi;   // phi sum, n=lane
                if (lane == 0) s_part[fr][wid * 5 + 4]    = v_psd;   // psd sum
            }
        }
    };

    // depth-2 ping-pong prefetch; frame count te-ts is always even (8 or 12)
    float4 La = *(const float4*)(xb + (size_t)ts * rowlen);
    float4 Lb = *(const float4*)(xb + (size_t)(ts + 1) * rowlen);
    for (int t = ts; t < te; t += 2) {
        frame(t, La);
        if (t + 2 < te) La = *(const float4*)(xb + (size_t)(t + 2) * rowlen);
        frame(t + 1, Lb);
        if (t + 3 < te) Lb = *(const float4*)(xb + (size_t)(t + 3) * rowlen);
    }

    __syncthreads();   // barrier 2 of 2: all frames' s_dcf + s_part visible

    // uniform epilogue: apply ratio, write final dcf for all output frames
    const int nf = te - t0;
    for (int fr = 0; fr < nf; ++fr) {
        const int t = t0 + fr;
        const size_t bt = (size_t)(b * NT + t);
        float dcfv = s_dcf[fr][tid];
        float dcf2v = extra ? s_dcf[fr][1024 + n] : 0.f;
        if (t >= 1) {
            const float* sp = s_part[fr];
            const float pre = sp[4] + sp[9] + sp[14] + sp[19] + sp[24];
            const float aft = sp[n] + sp[5 + n] + sp[10 + n] + sp[15 + n] + sp[20 + n];
            const float ratio = fminf(fmaxf(aft / (pre + 1e-10f), 0.01f), 1.0f);
            dcfv = sqrtf(dcfv * ratio);
            if (extra) dcf2v = sqrtf(dcf2v * ratio);
        }
        out[(bt * NF + f) * NNUL + n] = dcfv;
        if (extra) out[(bt * NF + 256) * NNUL + n] = dcf2v;
    }
}

extern "C" void kernel_launch(void* const* d_in, const int* in_sizes, int n_in,
                              void* d_out, int out_size, void* d_ws, size_t ws_size,
                              hipStream_t stream) {
    const float* x       = (const float*)d_in[0];
    const int*   beam_id = (const int*)d_in[1];
    const float* targ_w  = (const float*)d_in[2];
    const float* null_w  = (const float*)d_in[3];
    float* out           = (float*)d_out;
    (void)d_ws; (void)ws_size;

    dcf_fused_kernel<<<dim3(NB * N_CHUNK), dim3(1024), 0, stream>>>(
        x, beam_id, targ_w, null_w, out);
}